// Round 7
// baseline (362.549 us; speedup 1.0000x reference)
//
#include <hip/hip_runtime.h>
#include <hip/hip_fp16.h>
#include <math.h>

#define N_NODES 50000
#define N_EDGES 800000
#define N_GRAPHS 64
#define NEG_SLOPE 0.2f
#define SLOTS 64        // bucket capacity; P(in-degree>64) ~ 1e-20 for Poisson(16)

// ---- multisplit fill parameters ----
#define BIN_NODES 256                   // nodes per dst-range bin
#define NBINS 196                       // ceil(50000/256)
#define CAP 6144                        // u32 slots per bin (mean 4082, sigma ~64)
#define P1_BLOCKS 192                   // pass-1 blocks fused ahead of gemm0
#define BATCH 2048                      // edges per block-batch (8 per thread)

typedef _Float16 f16x8 __attribute__((ext_vector_type(8)));
typedef float f32x4 __attribute__((ext_vector_type(4)));

__device__ __forceinline__ float leaky(float x) {
    return x > 0.f ? x : NEG_SLOPE * x;
}

// ------- prep: W -> MFMA lane-major fp16 fragments; zero bin_cursor + d_out -------
__global__ __launch_bounds__(256) void prep_kernel(const float* __restrict__ W0,
                                                   const float* __restrict__ W1,
                                                   const float* __restrict__ W2,
                                                   _Float16* __restrict__ Wt0,
                                                   _Float16* __restrict__ Wt1,
                                                   _Float16* __restrict__ Wt2,
                                                   unsigned int* __restrict__ bin_cursor,
                                                   float* __restrict__ dout, int osz) {
    const int t = blockIdx.x * 256 + threadIdx.x;
    if (t < NBINS) bin_cursor[t] = 0;
    if (t < osz) dout[t] = 0.f;
    const float* W;
    _Float16* Wt;
    int g, CTl, DOUTl;
    if (t < 2048) { W = W0; Wt = Wt0; g = t; CTl = 8; DOUTl = 128; }
    else if (t < 4096) { W = W1; Wt = Wt1; g = t - 2048; CTl = 8; DOUTl = 128; }
    else if (t < 5120) { W = W2; Wt = Wt2; g = t - 4096; CTl = 4; DOUTl = 64; }
    else return;
    const int kt = g / (CTl * 64);
    const int rem = g % (CTl * 64);
    const int ct = rem / 64;
    const int lane = rem % 64;
    const int kbase = kt * 32 + (lane >> 4) * 8;
    const int c = ct * 16 + (lane & 15);
#pragma unroll
    for (int b = 0; b < 8; ++b)
        Wt[(size_t)g * 8 + b] = (_Float16)W[(size_t)(kbase + b) * DOUTl + c];
}

// ------- MFMA GEMM body: Hs(fp16, SLICE-MAJOR) = X @ W; as_/ad_ alphas -------
// Hs layout: [slice=col>>5][node][col&31] — 32-channel slices, 64B rows, so the
// sliced gather's per-XCD working set (3.2MB) fits its 4MB L2 (R7 theory).
template <int DOUT, typename XT>
__device__ __forceinline__ void mfma_gemm_body(const XT* __restrict__ X,
                                               const _Float16* __restrict__ Wt,
                                               const float* __restrict__ a_src,
                                               const float* __restrict__ a_dst,
                                               _Float16* __restrict__ Hs,
                                               float* __restrict__ as_,
                                               float* __restrict__ ad_, int N, int bid,
                                               _Float16* xs) {
    constexpr int CT = DOUT / 16;
    const int tid = threadIdx.x;
    const int n0 = bid * 64;

    if constexpr (sizeof(XT) == 4) {
        const float4* X4 = reinterpret_cast<const float4*>(X);
        for (int idx = tid; idx < 64 * 16; idx += 256) {
            const int r = idx >> 4, q = idx & 15;
            const int n = n0 + r;
            float4 v0 = make_float4(0.f, 0.f, 0.f, 0.f), v1 = v0;
            if (n < N) {
                v0 = X4[(size_t)n * 32 + 2 * q];
                v1 = X4[(size_t)n * 32 + 2 * q + 1];
            }
            f16x8 hv;
            hv[0] = (_Float16)v0.x; hv[1] = (_Float16)v0.y;
            hv[2] = (_Float16)v0.z; hv[3] = (_Float16)v0.w;
            hv[4] = (_Float16)v1.x; hv[5] = (_Float16)v1.y;
            hv[6] = (_Float16)v1.z; hv[7] = (_Float16)v1.w;
            *reinterpret_cast<f16x8*>(&xs[r * 128 + ((q ^ (r & 15)) << 3)]) = hv;
        }
    } else {
        const f16x8* X8 = reinterpret_cast<const f16x8*>(X);
        for (int idx = tid; idx < 64 * 16; idx += 256) {
            const int r = idx >> 4, q = idx & 15;
            const int n = n0 + r;
            f16x8 hv = {};
            if (n < N) hv = X8[(size_t)n * 16 + q];
            *reinterpret_cast<f16x8*>(&xs[r * 128 + ((q ^ (r & 15)) << 3)]) = hv;
        }
    }
    __syncthreads();

    const int wave = tid >> 6, lane = tid & 63;
    const int colb = lane & 15;
    const int kg = lane >> 4;
    const int arow = wave * 16 + colb;

    f32x4 acc[CT];
#pragma unroll
    for (int ct = 0; ct < CT; ++ct) {
        acc[ct][0] = 0.f; acc[ct][1] = 0.f; acc[ct][2] = 0.f; acc[ct][3] = 0.f;
    }
    const f16x8* Wt8 = reinterpret_cast<const f16x8*>(Wt);
#pragma unroll
    for (int kt = 0; kt < 4; ++kt) {
        f16x8 A = *reinterpret_cast<const f16x8*>(
            &xs[arow * 128 + (((kt * 4 + kg) ^ (arow & 15)) << 3)]);
#pragma unroll
        for (int ct = 0; ct < CT; ++ct) {
            f16x8 B = Wt8[(kt * CT + ct) * 64 + lane];
            acc[ct] = __builtin_amdgcn_mfma_f32_16x16x32_f16(A, B, acc[ct], 0, 0, 0);
        }
    }

    float ps[4] = {0.f, 0.f, 0.f, 0.f}, pd[4] = {0.f, 0.f, 0.f, 0.f};
#pragma unroll
    for (int ct = 0; ct < CT; ++ct) {
        const int col = ct * 16 + colb;
        const float asv = a_src[col];
        const float adv = a_dst[col];
        const size_t sbase = (size_t)(col >> 5) * N * 32 + (col & 31);
#pragma unroll
        for (int r = 0; r < 4; ++r) {
            const float d = acc[ct][r];
            ps[r] += d * asv;
            pd[r] += d * adv;
            const int row = n0 + wave * 16 + kg * 4 + r;
            if (row < N) Hs[sbase + (size_t)row * 32] = (_Float16)d;
        }
    }
#pragma unroll
    for (int off = 1; off < 16; off <<= 1) {
#pragma unroll
        for (int r = 0; r < 4; ++r) {
            ps[r] += __shfl_xor(ps[r], off, 64);
            pd[r] += __shfl_xor(pd[r], off, 64);
        }
    }
    if (colb == 0) {
#pragma unroll
        for (int r = 0; r < 4; ++r) {
            const int row = n0 + wave * 16 + kg * 4 + r;
            if (row < N) {
                as_[row] = ps[r];
                ad_[row] = pd[r];
            }
        }
    }
}

template <int DOUT, typename XT>
__global__ __launch_bounds__(256) void mfma_gemm_kernel(const XT* __restrict__ X,
                                                        const _Float16* __restrict__ Wt,
                                                        const float* __restrict__ a_src,
                                                        const float* __restrict__ a_dst,
                                                        _Float16* __restrict__ Hs,
                                                        float* __restrict__ as_,
                                                        float* __restrict__ ad_, int N) {
    __shared__ __align__(16) _Float16 xs[64 * 128];
    mfma_gemm_body<DOUT, XT>(X, Wt, a_src, a_dst, Hs, as_, ad_, N, blockIdx.x, xs);
}

// ------- pass 1: multisplit edges into 196 dst-range bins (packed u32 = d<<16|s) -------
struct P1Smem {
    unsigned int stage[BATCH];
    int hist[NBINS];
    int off[NBINS];
    unsigned int gbase[NBINS];
    int total;
};

__device__ __forceinline__ void fill_pass1(const int* __restrict__ src,
                                           const int* __restrict__ dst,
                                           unsigned int* __restrict__ bin_cursor,
                                           unsigned int* __restrict__ bin_buf,
                                           int E, int bid, void* smem_raw) {
    P1Smem& S = *reinterpret_cast<P1Smem*>(smem_raw);
    const int tid = threadIdx.x;
    const int nbatch = (E + BATCH - 1) / BATCH;
    for (int b = bid; b < nbatch; b += P1_BLOCKS) {
        __syncthreads();
        for (int i = tid; i < NBINS; i += 256) S.hist[i] = 0;
        const int e0 = b * BATCH;
        unsigned int pk[8];
        int rk[8];
        bool ok[8];
#pragma unroll
        for (int k = 0; k < 8; ++k) {
            int e = e0 + tid + k * 256;
            ok[k] = (e < E);
            int d = ok[k] ? dst[e] : 0;
            int s = ok[k] ? src[e] : 0;
            pk[k] = ((unsigned)d << 16) | (unsigned)s;
            rk[k] = 0;
        }
        __syncthreads();
#pragma unroll
        for (int k = 0; k < 8; ++k)
            if (ok[k]) rk[k] = atomicAdd(&S.hist[pk[k] >> 24], 1);
        __syncthreads();
        // parallel Hillis-Steele inclusive scan
        for (int i = tid; i < NBINS; i += 256) S.off[i] = S.hist[i];
        __syncthreads();
#pragma unroll
        for (int d = 1; d < 256; d <<= 1) {
            int v = 0;
            if (tid < NBINS && tid >= d) v = S.off[tid - d];
            __syncthreads();
            if (tid < NBINS) S.off[tid] += v;
            __syncthreads();
        }
        if (tid == NBINS - 1) S.total = S.off[NBINS - 1];
        __syncthreads();
        if (tid < NBINS) S.off[tid] -= S.hist[tid];  // exclusive
        __syncthreads();
        if (tid < NBINS && S.hist[tid] > 0)
            S.gbase[tid] = atomicAdd(&bin_cursor[tid], (unsigned)S.hist[tid]);
#pragma unroll
        for (int k = 0; k < 8; ++k)
            if (ok[k]) S.stage[S.off[pk[k] >> 24] + rk[k]] = pk[k];
        __syncthreads();
        const int tot = S.total;
        for (int i = tid; i < tot; i += 256) {
            unsigned int v = S.stage[i];
            int bn = v >> 24;
            unsigned int p = S.gbase[bn] + (unsigned)(i - S.off[bn]);
            if (p < CAP) bin_buf[(size_t)bn * CAP + p] = v;
        }
    }
}

// ------- fused layer-0 MFMA GEMM + pass-1 -------
__global__ __launch_bounds__(256) void gemm0_fill_kernel(
    const float* __restrict__ X, const _Float16* __restrict__ Wt0,
    const float* __restrict__ a_src, const float* __restrict__ a_dst,
    _Float16* __restrict__ Hs, float* __restrict__ as_, float* __restrict__ ad_, int N,
    const int* __restrict__ src, const int* __restrict__ dst,
    unsigned int* __restrict__ bin_cursor, unsigned int* __restrict__ bin_buf, int E) {
    __shared__ __align__(16) unsigned char smem[16384];  // union: P1Smem / xs
    if (blockIdx.x < P1_BLOCKS) {
        fill_pass1(src, dst, bin_cursor, bin_buf, E, blockIdx.x, smem);
        return;
    }
    mfma_gemm_body<128, float>(X, Wt0, a_src, a_dst, Hs, as_, ad_, N, blockIdx.x - P1_BLOCKS,
                               reinterpret_cast<_Float16*>(smem));
}

// ------- pass 2: per-bin bucket build in LDS, coalesced writeback -------
__global__ __launch_bounds__(256) void fill_pass2(const unsigned int* __restrict__ bin_cursor,
                                                  const unsigned int* __restrict__ bin_buf,
                                                  int* __restrict__ cursor,
                                                  unsigned short* __restrict__ col, int N) {
    __shared__ unsigned short bk[BIN_NODES][SLOTS];  // 32KB
    __shared__ int cnt[BIN_NODES];                   // 1KB
    const int b = blockIdx.x;
    const int tid = threadIdx.x;
    const int base = b * BIN_NODES;
    const int nn = min(BIN_NODES, N - base);
    if (nn <= 0) return;
    cnt[tid] = 0;
    __syncthreads();
    const int ec = min((int)bin_cursor[b], CAP);
    for (int i = tid; i < ec; i += 256) {
        unsigned int v = bin_buf[(size_t)b * CAP + i];
        int d = (int)(v >> 16) - base;
        int p = atomicAdd(&cnt[d], 1);
        if (p < SLOTS) bk[d][p] = (unsigned short)(v & 0xFFFFu);
    }
    __syncthreads();
    unsigned int* col32 = reinterpret_cast<unsigned int*>(col);
    const unsigned int* lds32 = reinterpret_cast<const unsigned int*>(&bk[0][0]);
    const int words = nn * (SLOTS / 2);
    for (int i = tid; i < words; i += 256)
        col32[(size_t)base * (SLOTS / 2) + i] = lds32[i];
    if (tid < nn) cursor[base + tid] = cnt[tid];
}

// ------- XCD-sliced softmax+gather: block = (slice s, 4 nodes), wave per node -------
// bid%8 -> XCD (round-robin, speed-only assumption): slice = (bid&7) & (S-1), so each
// XCD touches ONLY its 3.2MB slice of Hs -> fits 4MB L2 -> H fetch ~8x smaller.
// Per node-slice: 16 edge-subgroups x 4 lanes (8ch each). Softmax recomputed per
// slice (exp-lanes/edge actually DROP vs the old 32-lane-redundant version).
template <int S, bool POOL>
__global__ __launch_bounds__(256) void sgather_kernel(const _Float16* __restrict__ Hs,
                                                      const float* __restrict__ as_,
                                                      const float* __restrict__ ad_,
                                                      const int* __restrict__ cursor,
                                                      const unsigned short* __restrict__ col,
                                                      const float* __restrict__ bias,
                                                      _Float16* __restrict__ OUT,
                                                      const int* __restrict__ batch,
                                                      float* __restrict__ pool_out, int N) {
    __shared__ float pbuf[4][32];
    __shared__ int pg[4];
    const int j = blockIdx.x;
    const int x = j & 7;
    const int s = x & (S - 1);
    const int g = (j >> 3) * (8 / S) + (x / S);
    const int wv = threadIdx.x >> 6;
    const int node = g * 4 + wv;             // N%4==0, grid exact: node < N always
    const int l = threadIdx.x & 63;
    const int ch4 = l & 3;                   // 8-ch chunk within the 32-ch slice
    const int sub = l >> 2;                  // edge subgroup 0..15

    const _Float16* Hsl = Hs + (size_t)s * N * 32;
    const float adn = ad_[node];
    const float sl = leaky(as_[node] + adn);
    const int rs = node << 6;
    const int re = rs + min(cursor[node], SLOTS);

    float acc[8] = {};
    float dsum = 0.f;
    int i = rs + sub;
    for (; i + 16 < re; i += 32) {
        int s0 = col[i];
        int s1 = col[i + 16];
        float e0 = __expf(leaky(as_[s0] + adn));
        float e1 = __expf(leaky(as_[s1] + adn));
        f16x8 h0 = *reinterpret_cast<const f16x8*>(&Hsl[(size_t)s0 * 32 + ch4 * 8]);
        f16x8 h1 = *reinterpret_cast<const f16x8*>(&Hsl[(size_t)s1 * 32 + ch4 * 8]);
#pragma unroll
        for (int q = 0; q < 8; ++q)
            acc[q] += e0 * (float)h0[q] + e1 * (float)h1[q];
        dsum += e0 + e1;
    }
    if (i < re) {
        int s0 = col[i];
        float e0 = __expf(leaky(as_[s0] + adn));
        f16x8 h0 = *reinterpret_cast<const f16x8*>(&Hsl[(size_t)s0 * 32 + ch4 * 8]);
#pragma unroll
        for (int q = 0; q < 8; ++q)
            acc[q] += e0 * (float)h0[q];
        dsum += e0;
    }

    // dsum identical across the 4 lanes of a subgroup; combine the 16 subgroups
#pragma unroll
    for (int off = 4; off <= 32; off <<= 1)
        dsum += __shfl_xor(dsum, off, 64);
#pragma unroll
    for (int off = 32; off >= 4; off >>= 1) {
#pragma unroll
        for (int q = 0; q < 8; ++q)
            acc[q] += __shfl_down(acc[q], off, 64);
    }

    if (l < 4) {
        const float e_self = __expf(sl);
        f16x8 hself = *reinterpret_cast<const f16x8*>(&Hsl[(size_t)node * 32 + ch4 * 8]);
        const float inv = 1.f / (dsum + e_self);
        const float4* b4 = reinterpret_cast<const float4*>(bias + s * 32);
        const float4 ba = b4[2 * ch4], bb = b4[2 * ch4 + 1];
        const float bj[8] = {ba.x, ba.y, ba.z, ba.w, bb.x, bb.y, bb.z, bb.w};
        float r[8];
#pragma unroll
        for (int q = 0; q < 8; ++q) {
            r[q] = (acc[q] + e_self * (float)hself[q]) * inv + bj[q];
            if (!POOL) r[q] = fmaxf(r[q], 0.f);  // relu on layers 0/1
        }
        if (POOL) {
#pragma unroll
            for (int q = 0; q < 8; ++q) pbuf[wv][ch4 * 8 + q] = r[q];
        } else {
            f16x8 o;
#pragma unroll
            for (int q = 0; q < 8; ++q) o[q] = (_Float16)r[q];
            *reinterpret_cast<f16x8*>(&OUT[(size_t)node * 128 + s * 32 + ch4 * 8]) = o;
        }
    }
    if (POOL) {
        if (l == 0) pg[wv] = batch[node];
        __syncthreads();
        if (threadIdx.x < 32) {
            const int c = threadIdx.x;
            const int g0 = pg[0], g3 = pg[3];
            if (g0 == g3) {  // batch sorted: common case, one atomic
                atomicAdd(&pool_out[g0 * 64 + s * 32 + c],
                          pbuf[0][c] + pbuf[1][c] + pbuf[2][c] + pbuf[3][c]);
            } else {
#pragma unroll
                for (int w = 0; w < 4; ++w)
                    atomicAdd(&pool_out[pg[w] * 64 + s * 32 + c], pbuf[w][c]);
            }
        }
    }
}

extern "C" void kernel_launch(void* const* d_in, const int* in_sizes, int n_in,
                              void* d_out, int out_size, void* d_ws, size_t ws_size,
                              hipStream_t stream) {
    const float* x = (const float*)d_in[0];
    const int* edge_index = (const int*)d_in[1];
    const int* batch = (const int*)d_in[2];
    const float* W0 = (const float*)d_in[3];
    const float* as0 = (const float*)d_in[4];
    const float* ad0 = (const float*)d_in[5];
    const float* b0 = (const float*)d_in[6];
    const float* W1 = (const float*)d_in[7];
    const float* as1 = (const float*)d_in[8];
    const float* ad1 = (const float*)d_in[9];
    const float* b1 = (const float*)d_in[10];
    const float* W2 = (const float*)d_in[11];
    const float* as2 = (const float*)d_in[12];
    const float* ad2 = (const float*)d_in[13];
    const float* b2 = (const float*)d_in[14];

    const int* e_src = edge_index;            // row 0
    const int* e_dst = edge_index + N_EDGES;  // row 1

    // workspace layout (byte-based; every region 16B-aligned)
    char* p = (char*)d_ws;
    _Float16* X16 = (_Float16*)p;     p += (size_t)N_NODES * 128 * 2;   // 12.8MB fp16 intermediate
    _Float16* Hs = (_Float16*)p;      p += (size_t)N_NODES * 128 * 2;   // 12.8MB slice-major H
    float* as_ = (float*)p;           p += (size_t)N_NODES * 4;
    float* ad_ = (float*)p;           p += (size_t)N_NODES * 4;
    int* cursor = (int*)p;            p += (size_t)N_NODES * 4;
    unsigned short* col = (unsigned short*)p; p += (size_t)N_NODES * SLOTS * 2;  // 6.4MB
    unsigned int* bin_cursor = (unsigned int*)p; p += (size_t)((NBINS + 3) & ~3) * 4;
    unsigned int* bin_buf = (unsigned int*)p; p += (size_t)NBINS * CAP * 4;      // 4.8MB
    _Float16* Wt0 = (_Float16*)p;     p += (size_t)16384 * 2;
    _Float16* Wt1 = (_Float16*)p;     p += (size_t)16384 * 2;
    _Float16* Wt2 = (_Float16*)p;     p += (size_t)8192 * 2;

    const int GEMM_BLOCKS = (N_NODES + 63) / 64;
    const int SG4_BLOCKS = (N_NODES / 4) * 4;   // 12500 groups x S=4 = 50000
    const int SG2_BLOCKS = (N_NODES / 4) * 2;   // 12500 groups x S=2 = 25000

    // ---- prep: W fragments + bin_cursor zero + d_out zero ----
    prep_kernel<<<20, 256, 0, stream>>>(W0, W1, W2, Wt0, Wt1, Wt2, bin_cursor,
                                        (float*)d_out, out_size);

    // ---- layer 0 MFMA gemm fused with fill pass-1 ----
    gemm0_fill_kernel<<<P1_BLOCKS + GEMM_BLOCKS, 256, 0, stream>>>(
        x, Wt0, as0, ad0, Hs, as_, ad_, N_NODES, e_src, e_dst, bin_cursor, bin_buf, N_EDGES);
    fill_pass2<<<NBINS, 256, 0, stream>>>(bin_cursor, bin_buf, cursor, col, N_NODES);
    sgather_kernel<4, false><<<SG4_BLOCKS, 256, 0, stream>>>(
        Hs, as_, ad_, cursor, col, b0, X16, batch, nullptr, N_NODES);

    // ---- layer 1: X16 -> Hs ----
    mfma_gemm_kernel<128, _Float16><<<GEMM_BLOCKS, 256, 0, stream>>>(
        X16, Wt1, as1, ad1, Hs, as_, ad_, N_NODES);
    sgather_kernel<4, false><<<SG4_BLOCKS, 256, 0, stream>>>(
        Hs, as_, ad_, cursor, col, b1, X16, batch, nullptr, N_NODES);

    // ---- layer 2: X16 -> Hs (64-wide = 2 slices), gather fused with pool ----
    mfma_gemm_kernel<64, _Float16><<<GEMM_BLOCKS, 256, 0, stream>>>(
        X16, Wt2, as2, ad2, Hs, as_, ad_, N_NODES);
    sgather_kernel<2, true><<<SG2_BLOCKS, 256, 0, stream>>>(
        Hs, as_, ad_, cursor, col, b2, nullptr, batch, (float*)d_out, N_NODES);
}